// Round 1
// baseline (264.613 us; speedup 1.0000x reference)
//
#include <hip/hip_runtime.h>
#include <math.h>

// TimeNormalization: EMA over time (alpha=0.1) of x and x^2, then normalize.
// x: [B=32, T=8192, F=128] fp32; state: [2,B,F] fp32 (s_{-1}).
// Outputs (concatenated in d_out): x_norm [B,T,F] fp32, final_state [2,B,F] fp32.
//
// Strategy: chunked-parallel with warmup. EMA decay 0.9^128 ~ 1.4e-6, so each
// chunk of L=256 timesteps warms up over the previous W=128 steps from zero
// state (chunk 0 uses the exact initial state). Error << 6.1e-2 threshold.
// Fully parallel: grid = (T/L) x B blocks of F threads, coalesced loads
// (128 consecutive floats per (b,t) row).

constexpr int B = 32, T = 8192, F = 128;
constexpr int L = 256;          // chunk length
constexpr int W = 128;          // warmup window (0.9^128 ~ 1.4e-6)
constexpr int NCHUNK = T / L;   // 32
constexpr float ALPHA = 0.1f;
constexpr float CDECAY = 0.9f;  // 1 - ALPHA
constexpr float EPS = 1e-3f;

__global__ __launch_bounds__(F) void TimeNormalization_kernel(
    const float* __restrict__ x,
    const float* __restrict__ state,
    float* __restrict__ out) {
    const int f = threadIdx.x;        // 0..127, stride-1 in memory -> coalesced
    const int chunk = blockIdx.x;     // 0..NCHUNK-1
    const int b = blockIdx.y;         // 0..B-1
    const int t0 = chunk * L;

    float sm, ss;
    int t;
    if (chunk == 0) {
        // exact initial state s_{-1}
        sm = state[b * F + f];
        ss = state[B * F + b * F + f];
        t = 0;
    } else {
        sm = 0.0f;
        ss = 0.0f;
        t = t0 - W;   // >= 128 for chunk >= 1
    }

    const float* __restrict__ px = x + (size_t)b * T * F + f;
    float* __restrict__ po = out + (size_t)b * T * F + f;

    // Warmup: build up state, no output. Loads independent -> pipelined.
    #pragma unroll 4
    for (; t < t0; ++t) {
        float xv = px[(size_t)t * F];
        sm = fmaf(CDECAY, sm, ALPHA * xv);
        ss = fmaf(CDECAY, ss, ALPHA * (xv * xv));
    }

    // Main: update state, normalize, store.
    #pragma unroll 4
    for (int i = 0; i < L; ++i) {
        const int tt = t0 + i;
        float xv = px[(size_t)tt * F];
        sm = fmaf(CDECAY, sm, ALPHA * xv);
        ss = fmaf(CDECAY, ss, ALPHA * (xv * xv));
        float var = ss - sm * sm;
        po[(size_t)tt * F] = (xv - sm) * rsqrtf(var + EPS);
    }

    // Last chunk owns the final state output.
    if (chunk == NCHUNK - 1) {
        float* fs = out + (size_t)B * T * F;
        fs[b * F + f] = sm;              // mean state
        fs[B * F + b * F + f] = ss;      // second-moment state
    }
}

extern "C" void kernel_launch(void* const* d_in, const int* in_sizes, int n_in,
                              void* d_out, int out_size, void* d_ws, size_t ws_size,
                              hipStream_t stream) {
    const float* x = (const float*)d_in[0];
    const float* state = (const float*)d_in[1];
    float* out = (float*)d_out;

    dim3 grid(NCHUNK, B);
    dim3 block(F);
    TimeNormalization_kernel<<<grid, block, 0, stream>>>(x, state, out);
}

// Round 2
// 255.322 us; speedup vs baseline: 1.0364x; 1.0364x over previous
//
#include <hip/hip_runtime.h>
#include <math.h>

// TimeNormalization: EMA over time (alpha=0.1) of x and x^2, then normalize.
// x: [B=32, T=8192, F=128] fp32; state: [2,B,F] fp32 (s_{-1}).
// Outputs (concat in d_out): x_norm [B,T,F] fp32, final_state [2,B,F] fp32.
//
// Chunked-parallel with warmup: 0.9^128 ~ 1.4e-6, so each chunk of L=128
// steps warms up over the previous W=128 steps from zero state (chunk 0 uses
// the exact initial state). R1 post-mortem: latency/occupancy-bound
// (occ 17.8%, 2.2 TB/s) -> L=128 doubles grid to 2048 blocks (16 waves/CU),
// unroll 8 doubles loads-in-flight, nontemporal stores keep x L3-resident.

constexpr int B = 32, T = 8192, F = 128;
constexpr int L = 128;          // chunk length (R1: 256 -> grid-limited occupancy)
constexpr int W = 128;          // warmup window (0.9^128 ~ 1.4e-6)
constexpr int NCHUNK = T / L;   // 64
constexpr float ALPHA = 0.1f;
constexpr float CDECAY = 0.9f;  // 1 - ALPHA
constexpr float EPS = 1e-3f;

__global__ __launch_bounds__(F) void TimeNormalization_kernel(
    const float* __restrict__ x,
    const float* __restrict__ state,
    float* __restrict__ out) {
    const int f = threadIdx.x;        // 0..127, stride-1 -> coalesced
    const int chunk = blockIdx.x;     // 0..NCHUNK-1
    const int b = blockIdx.y;         // 0..B-1
    const int t0 = chunk * L;

    float sm, ss;
    int t;
    if (chunk == 0) {
        sm = state[b * F + f];            // exact initial state s_{-1}
        ss = state[B * F + b * F + f];
        t = 0;
    } else {
        sm = 0.0f;
        ss = 0.0f;
        t = t0 - W;                       // >= 0 for chunk >= 1 (W == L)
    }

    const float* __restrict__ px = x + (size_t)b * T * F + f;
    float* __restrict__ po = out + (size_t)b * T * F + f;

    // Warmup: build up state, no output. Loads independent -> deep pipeline.
    #pragma unroll 8
    for (; t < t0; ++t) {
        float xv = px[(size_t)t * F];
        sm = fmaf(CDECAY, sm, ALPHA * xv);
        ss = fmaf(CDECAY, ss, ALPHA * (xv * xv));
    }

    // Main: update state, normalize, nontemporal store (streaming output
    // must not evict x from L2/L3 -- warmup reads rely on L3 hits).
    #pragma unroll 8
    for (int i = 0; i < L; ++i) {
        const int tt = t0 + i;
        float xv = px[(size_t)tt * F];
        sm = fmaf(CDECAY, sm, ALPHA * xv);
        ss = fmaf(CDECAY, ss, ALPHA * (xv * xv));
        float var = ss - sm * sm;
        float o = (xv - sm) * rsqrtf(var + EPS);
        __builtin_nontemporal_store(o, &po[(size_t)tt * F]);
    }

    // Last chunk owns the final-state output.
    if (chunk == NCHUNK - 1) {
        float* fs = out + (size_t)B * T * F;
        fs[b * F + f] = sm;              // mean state
        fs[B * F + b * F + f] = ss;      // second-moment state
    }
}

extern "C" void kernel_launch(void* const* d_in, const int* in_sizes, int n_in,
                              void* d_out, int out_size, void* d_ws, size_t ws_size,
                              hipStream_t stream) {
    const float* x = (const float*)d_in[0];
    const float* state = (const float*)d_in[1];
    float* out = (float*)d_out;

    dim3 grid(NCHUNK, B);
    dim3 block(F);
    TimeNormalization_kernel<<<grid, block, 0, stream>>>(x, state, out);
}

// Round 4
// 250.563 us; speedup vs baseline: 1.0561x; 1.0190x over previous
//
#include <hip/hip_runtime.h>
#include <math.h>

// TimeNormalization: EMA over time (alpha=0.1) of x and x^2, then normalize.
// x: [B=32, T=8192, F=128] fp32; state: [2,B,F] fp32 (s_{-1}).
// Outputs (concat in d_out): x_norm [B,T,F] fp32, final_state [2,B,F] fp32.
//
// Chunked-parallel with warmup: 0.9^128 ~ 1.4e-6, so each chunk of L=128
// steps warms up over the previous W=128 steps from zero state (chunk 0 uses
// the exact initial state).
//
// R2 post-mortem: BW stuck at 2.7 TB/s = ~15 outstanding 256B wave-requests
// per CU -> the cap is on REQUESTS, not bytes. R3/R4: float4 per lane
// (worker = 32 lanes per F-row) -> 1024B per wave-request, 4x bytes per
// request slot. R4 fixes R3's compile error: __builtin_nontemporal_store
// needs a clang ext_vector_type, not HIP's struct float4.

constexpr int B = 32, T = 8192, F = 128;
constexpr int L = 128;          // chunk length
constexpr int W = 128;          // warmup window (0.9^128 ~ 1.4e-6)
constexpr int NCHUNK = T / L;   // 64
constexpr int F4 = F / 4;       // 32 float4 lanes per row
constexpr int WPB = 8;          // workers per 256-thread block
constexpr float ALPHA = 0.1f;
constexpr float CDECAY = 0.9f;  // 1 - ALPHA
constexpr float EPS = 1e-3f;

typedef float v4f __attribute__((ext_vector_type(4)));

__global__ __launch_bounds__(256) void TimeNormalization_kernel(
    const float* __restrict__ x,
    const float* __restrict__ state,
    float* __restrict__ out) {
    const int j = threadIdx.x & 31;                       // v4f lane in row
    const int w = blockIdx.x * WPB + (threadIdx.x >> 5);  // worker id
    const int b = w >> 6;        // w / NCHUNK
    const int chunk = w & 63;    // w % NCHUNK
    const int t0 = chunk * L;

    const v4f* __restrict__ x4 = (const v4f*)x;
    const v4f* __restrict__ s4 = (const v4f*)state;
    v4f* __restrict__ o4 = (v4f*)out;

    v4f sm, ss;
    int t;
    if (chunk == 0) {
        sm = s4[b * F4 + j];                 // exact initial state s_{-1}
        ss = s4[B * F4 + b * F4 + j];
        t = 0;
    } else {
        sm = (v4f)0.f;
        ss = (v4f)0.f;
        t = t0 - W;                          // >= 0 for chunk >= 1 (W == L)
    }

    const v4f* __restrict__ px = x4 + (size_t)b * T * F4 + j;
    v4f* __restrict__ po = o4 + (size_t)b * T * F4 + j;

    // Warmup: build state, no output. Independent 16B loads -> deep pipeline.
    #pragma unroll 8
    for (; t < t0; ++t) {
        v4f v = px[(size_t)t * F4];
        sm = CDECAY * sm + ALPHA * v;        // vector fma
        ss = CDECAY * ss + ALPHA * (v * v);
    }

    // Main: update state, normalize, nontemporal 16B store (streaming output
    // must not evict x from L2/L3 -- warmup reads rely on cache hits).
    #pragma unroll 8
    for (int i = 0; i < L; ++i) {
        const int tt = t0 + i;
        v4f v = px[(size_t)tt * F4];
        sm = CDECAY * sm + ALPHA * v;
        ss = CDECAY * ss + ALPHA * (v * v);
        v4f d = v - sm;
        v4f o;
        o.x = d.x * rsqrtf(ss.x - sm.x * sm.x + EPS);
        o.y = d.y * rsqrtf(ss.y - sm.y * sm.y + EPS);
        o.z = d.z * rsqrtf(ss.z - sm.z * sm.z + EPS);
        o.w = d.w * rsqrtf(ss.w - sm.w * sm.w + EPS);
        __builtin_nontemporal_store(o, &po[(size_t)tt * F4]);
    }

    // Last chunk owns the final-state output.
    if (chunk == NCHUNK - 1) {
        v4f* fs = (v4f*)(out + (size_t)B * T * F);
        fs[b * F4 + j] = sm;                 // mean state
        fs[B * F4 + b * F4 + j] = ss;        // second-moment state
    }
}

extern "C" void kernel_launch(void* const* d_in, const int* in_sizes, int n_in,
                              void* d_out, int out_size, void* d_ws, size_t ws_size,
                              hipStream_t stream) {
    const float* x = (const float*)d_in[0];
    const float* state = (const float*)d_in[1];
    float* out = (float*)d_out;

    dim3 grid((B * NCHUNK) / WPB);   // 256 blocks
    dim3 block(256);                 // 8 workers of 32 lanes each
    TimeNormalization_kernel<<<grid, block, 0, stream>>>(x, state, out);
}